// Round 1
// baseline (1317.617 us; speedup 1.0000x reference)
//
#include <hip/hip_runtime.h>
#include <hip/hip_bf16.h>

#define GLOBAL_AS __attribute__((address_space(1)))
#define LDS_AS    __attribute__((address_space(3)))

typedef __bf16 bf16_t;
typedef __bf16 bf16x8 __attribute__((ext_vector_type(8)));
typedef __bf16 bf16x4 __attribute__((ext_vector_type(4)));
typedef float  f32x4  __attribute__((ext_vector_type(4)));

static constexpr int Bb = 256;    // batch
static constexpr int Ss = 14;     // seq
static constexpr int Hh = 1024;   // hidden
static constexpr int Cc = 2513;   // classes
static constexpr int G4 = 4096;   // 4H
static constexpr int NXc = 3584;  // B*S
static constexpr int Kk = 1024;   // K (== F == H)

__device__ __forceinline__ float sigm(float x)   { return 1.0f / (1.0f + __expf(-x)); }
__device__ __forceinline__ float tanh_f(float x) { return 2.0f / (1.0f + __expf(-2.0f * x)) - 1.0f; }

// ---------------------------------------------------------------------------
// Generic bf16 GEMM: C[M,N] = A[M,K] @ B[N,K]^T, K=1024, 128x128 tile, BK=64.
// EPI 0: XG store  — rows are 4n+g; add row-bias; store float4 to XG2[n][col][4]
// EPI 1: LSTM cell — rows are 4n+g; lane's 4 regs = gates (i,f,g,o) of (n,col);
//                    col = t*256+b (t_base added for roll); fused state update.
// EPI 2: plain     — add col-bias, bounds-checked store (classifier).
// ---------------------------------------------------------------------------
template<int EPI>
__global__ __launch_bounds__(256, 2)
void gemm_bt(const bf16_t* __restrict__ A, const bf16_t* __restrict__ Bm,
             int N,
             const float* __restrict__ e_bias,
             float* __restrict__ xg_or_out,
             const float* __restrict__ c_src,
             float* __restrict__ c_dst,
             bf16_t* __restrict__ h_dst,
             int t_base)
{
    __shared__ char smem[32768];              // A tile 16K | B tile 16K
    LDS_AS char* sA = (LDS_AS char*)smem;
    LDS_AS char* sB = sA + 16384;

    const int tid  = threadIdx.x;
    const int lane = tid & 63;
    const int wave = tid >> 6;
    const int row0 = blockIdx.x * 128;
    const int col0 = blockIdx.y * 128;
    const int mwb  = (wave >> 1) * 64;
    const int nwb  = (wave & 1) * 64;
    const int quad = lane >> 4;
    const int l15  = lane & 15;

    f32x4 acc[4][4] = {};

    for (int kb = 0; kb < Kk; kb += 64) {
        // ---- stage A,B tiles: 16B/lane, XOR-swizzled k-chunks ----
#pragma unroll
        for (int it = 0; it < 4; ++it) {
            int c  = it * 256 + tid;
            int m  = c >> 3;
            int kq = (c & 7) ^ (m & 7);
            const bf16_t* ga = A + (size_t)(row0 + m) * Kk + kb + kq * 8;
            int nr = col0 + m;
            if (EPI == 2) { if (nr >= N) nr = 0; }      // classifier N-edge clamp
            const bf16_t* gb = Bm + (size_t)nr * Kk + kb + kq * 8;
            LDS_AS char* la = sA + (size_t)(it * 256 + (tid & 192)) * 16;
            LDS_AS char* lb = sB + (size_t)(it * 256 + (tid & 192)) * 16;
            __builtin_amdgcn_global_load_lds((const GLOBAL_AS void*)ga, (LDS_AS void*)la, 16, 0, 0);
            __builtin_amdgcn_global_load_lds((const GLOBAL_AS void*)gb, (LDS_AS void*)lb, 16, 0, 0);
        }
        __syncthreads();

        // ---- compute: 2 k-steps x 16 MFMAs ----
#pragma unroll
        for (int kt = 0; kt < 2; ++kt) {
            bf16x8 af[4], bfr[4];
            const int kq = kt * 4 + quad;
#pragma unroll
            for (int i = 0; i < 4; ++i) {
                int ml = mwb + i * 16 + l15;
                af[i]  = *(const LDS_AS bf16x8*)(sA + (size_t)(ml * 8 + (kq ^ (ml & 7))) * 16);
                int nl = nwb + i * 16 + l15;
                bfr[i] = *(const LDS_AS bf16x8*)(sB + (size_t)(nl * 8 + (kq ^ (nl & 7))) * 16);
            }
#pragma unroll
            for (int i = 0; i < 4; ++i)
#pragma unroll
                for (int j = 0; j < 4; ++j)
                    acc[i][j] = __builtin_amdgcn_mfma_f32_16x16x32_bf16(af[i], bfr[j], acc[i][j], 0, 0, 0);
        }
        __syncthreads();
    }

    // ---- epilogue ----
#pragma unroll
    for (int im = 0; im < 4; ++im) {
#pragma unroll
        for (int jn = 0; jn < 4; ++jn) {
            const int rb  = row0 + mwb + im * 16 + quad * 4;  // 4 consecutive rows
            const int col = col0 + nwb + jn * 16 + l15;
            f32x4 v = acc[im][jn];
            if (EPI == 0) {
                const int n = rb >> 2;
                f32x4 bi = *(const f32x4*)(e_bias + n * 4);
                v[0] += bi[0]; v[1] += bi[1]; v[2] += bi[2]; v[3] += bi[3];
                *(f32x4*)(xg_or_out + ((size_t)n * NXc + col) * 4) = v;
            } else if (EPI == 1) {
                const int n = rb >> 2;
                const int t = (col >> 8) + t_base;
                const int b = col & 255;
                f32x4 xg = *(const f32x4*)(xg_or_out + ((size_t)n * NXc + (b * Ss + t)) * 4);
                float gi = v[0] + xg[0];
                float gf = v[1] + xg[1];
                float gg = v[2] + xg[2];
                float go = v[3] + xg[3];
                const size_t sidx = (size_t)col * Hh + n;
                float c2 = sigm(gf) * c_src[sidx] + sigm(gi) * tanh_f(gg);
                float h2 = sigm(go) * tanh_f(c2);
                c_dst[sidx] = c2;
                h_dst[sidx] = (bf16_t)h2;
            } else {
                if (col < N) {
                    float bi = e_bias[col];
#pragma unroll
                    for (int g = 0; g < 4; ++g)
                        xg_or_out[(size_t)(rb + g) * N + col] = v[g] + bi;
                }
            }
        }
    }
}

// ---------------------------------------------------------------------------
// Weight conversion: fp32 [4H,K] -> bf16 [4H,K] with row perm 4n+g <- g*H+n
// 4 matrices in one launch; 4 elements/thread.
// ---------------------------------------------------------------------------
__global__ void cvt_w(const float* __restrict__ a0, const float* __restrict__ a1,
                      const float* __restrict__ a2, const float* __restrict__ a3,
                      bf16_t* __restrict__ o0, bf16_t* __restrict__ o1,
                      bf16_t* __restrict__ o2, bf16_t* __restrict__ o3)
{
    int idx = blockIdx.x * 256 + threadIdx.x;          // 4 * 1,048,576 threads
    int mat = idx >> 20;
    int r   = (idx >> 8) & 4095;                       // output row (4n+g)
    int k4  = (idx & 255) * 4;
    int n = r >> 2, g = r & 3;
    const float* src = mat == 0 ? a0 : mat == 1 ? a1 : mat == 2 ? a2 : a3;
    bf16_t*      dst = mat == 0 ? o0 : mat == 1 ? o1 : mat == 2 ? o2 : o3;
    f32x4 v = *(const f32x4*)(src + (size_t)(g * Hh + n) * Kk + k4);
    bf16x4 o;
    o[0] = (bf16_t)v[0]; o[1] = (bf16_t)v[1]; o[2] = (bf16_t)v[2]; o[3] = (bf16_t)v[3];
    *(bf16x4*)(dst + (size_t)r * Kk + k4) = o;
}

__global__ void cvt_bias(const float* __restrict__ bih_r, const float* __restrict__ bhh_r,
                         const float* __restrict__ bih_u, const float* __restrict__ bhh_u,
                         float* __restrict__ br, float* __restrict__ bu)
{
    int r = blockIdx.x * 256 + threadIdx.x;            // 4096
    int n = r >> 2, g = r & 3;
    int ir = g * Hh + n;
    br[r] = bih_r[ir] + bhh_r[ir];
    bu[r] = bih_u[ir] + bhh_u[ir];
}

__global__ void cast_f32_bf16(const float* __restrict__ src, bf16_t* __restrict__ dst, int n4)
{
    int i = blockIdx.x * 256 + threadIdx.x;
    if (i < n4) {
        f32x4 v = *(const f32x4*)(src + (size_t)i * 4);
        bf16x4 o;
        o[0] = (bf16_t)v[0]; o[1] = (bf16_t)v[1]; o[2] = (bf16_t)v[2]; o[3] = (bf16_t)v[3];
        *(bf16x4*)(dst + (size_t)i * 4) = o;
    }
}

// preds[b*14+s][:] = Hu[(15-s)&1][s][b][:]   (16B per thread)
__global__ void gather_preds(const bf16_t* __restrict__ Hu0, const bf16_t* __restrict__ Hu1,
                             bf16_t* __restrict__ preds)
{
    int idx = blockIdx.x * 256 + threadIdx.x;          // 3584*128
    int h8  = (idx & 127) * 8;
    int row = idx >> 7;                                // b*14 + s
    int s = row % 14;
    int b = row / 14;
    const bf16_t* src = (((15 - s) & 1) ? Hu1 : Hu0) + (((size_t)(s * 256 + b)) << 10) + h8;
    *(uint4*)(preds + ((size_t)row << 10) + h8) = *(const uint4*)src;
}

// ---------------------------------------------------------------------------
extern "C" void kernel_launch(void* const* d_in, const int* in_sizes, int n_in,
                              void* d_out, int out_size, void* d_ws, size_t ws_size,
                              hipStream_t stream)
{
    const float* Wih_r = (const float*)d_in[1];
    const float* Whh_r = (const float*)d_in[2];
    const float* bih_r = (const float*)d_in[3];
    const float* bhh_r = (const float*)d_in[4];
    const float* Wih_u = (const float*)d_in[5];
    const float* Whh_u = (const float*)d_in[6];
    const float* bih_u = (const float*)d_in[7];
    const float* bhh_u = (const float*)d_in[8];
    const float* Wc    = (const float*)d_in[9];
    const float* bc    = (const float*)d_in[10];
    const float* x_in  = (const float*)d_in[0];
    float* out = (float*)d_out;

    char* ws = (char*)d_ws;
    size_t off = 0;
    auto alloc = [&](size_t bytes) -> char* {
        char* p = ws + off;
        off += (bytes + 255) & ~(size_t)255;
        return p;
    };

    const size_t BH = (size_t)Bb * Hh;                 // 262144 elems
    bf16_t* w_ihr = (bf16_t*)alloc((size_t)G4 * Kk * 2);
    bf16_t* w_hhr = (bf16_t*)alloc((size_t)G4 * Kk * 2);
    bf16_t* w_ihu = (bf16_t*)alloc((size_t)G4 * Kk * 2);
    bf16_t* w_hhu = (bf16_t*)alloc((size_t)G4 * Kk * 2);
    bf16_t* wc_b  = (bf16_t*)alloc((size_t)Cc * Kk * 2);
    bf16_t* x_b   = (bf16_t*)alloc((size_t)NXc * Kk * 2);
    float*  bias_r = (float*)alloc(G4 * 4);
    float*  bias_u = (float*)alloc(G4 * 4);
    float*  XG_r  = (float*)alloc((size_t)Hh * NXc * 4 * 4);   // [n][col][4]
    float*  XG_u  = (float*)alloc((size_t)Hh * NXc * 4 * 4);
    bf16_t* Hu0   = (bf16_t*)alloc((size_t)Ss * BH * 2);
    bf16_t* Hu1   = (bf16_t*)alloc((size_t)Ss * BH * 2);
    float*  Cu    = (float*)alloc((size_t)Ss * BH * 4);
    bf16_t* h0    = (bf16_t*)alloc(BH * 2);
    float*  c0    = (float*)alloc(BH * 4);
    bf16_t* preds = (bf16_t*)alloc((size_t)NXc * Kk * 2);

    // zero initial states
    hipMemsetAsync(h0, 0, BH * 2, stream);
    hipMemsetAsync(c0, 0, BH * 4, stream);

    // conversions
    cvt_w<<<16384, 256, 0, stream>>>(Wih_r, Whh_r, Wih_u, Whh_u, w_ihr, w_hhr, w_ihu, w_hhu);
    cvt_bias<<<16, 256, 0, stream>>>(bih_r, bhh_r, bih_u, bhh_u, bias_r, bias_u);
    cast_f32_bf16<<<(NXc * Kk / 4 + 255) / 256, 256, 0, stream>>>(x_in, x_b, NXc * Kk / 4);
    cast_f32_bf16<<<(Cc * Kk / 4 + 255) / 256, 256, 0, stream>>>(Wc, wc_b, Cc * Kk / 4);

    // input-projection GEMMs: XG = W_perm @ x^T + bias  -> [n][b*14+s][4]
    gemm_bt<0><<<dim3(32, 28), 256, 0, stream>>>(w_ihr, x_b, NXc, bias_r, XG_r,
                                                 nullptr, nullptr, nullptr, 0);
    gemm_bt<0><<<dim3(32, 28), 256, 0, stream>>>(w_ihu, x_b, NXc, bias_u, XG_u,
                                                 nullptr, nullptr, nullptr, 0);

    // rolling LSTM: 14 sequential steps; hs[t] -> Hu0[t], cs[t] -> Cu[t]
    for (int t = 0; t < Ss; ++t) {
        const bf16_t* hprev = (t == 0) ? h0 : (Hu0 + (size_t)(t - 1) * BH);
        const float*  csrc  = (t == 0) ? c0 : (Cu + (size_t)(t - 1) * BH);
        gemm_bt<1><<<dim3(32, 2), 256, 0, stream>>>(w_hhr, hprev, 256, nullptr, XG_r,
                                                    csrc, Cu + (size_t)t * BH,
                                                    Hu0 + (size_t)t * BH, t);
    }

    // unrolling LSTM: 15 batched steps over shrinking active-t prefix
    for (int j = 1; j <= 15; ++j) {
        int a = 16 - j; if (a > 14) a = 14;
        const bf16_t* hread = (j & 1) ? Hu0 : Hu1;
        bf16_t*       hwrit = (j & 1) ? Hu1 : Hu0;
        gemm_bt<1><<<dim3(32, 2 * a), 256, 0, stream>>>(w_hhu, hread, a * 256, nullptr, XG_u,
                                                        Cu, Cu, hwrit, 0);
    }

    // gather preds [b*14+s][:] then classifier
    gather_preds<<<1792, 256, 0, stream>>>(Hu0, Hu1, preds);
    gemm_bt<2><<<dim3(28, 20), 256, 0, stream>>>(preds, wc_b, Cc, bc, out,
                                                 nullptr, nullptr, nullptr, 0);
}

// Round 2
// 950.567 us; speedup vs baseline: 1.3861x; 1.3861x over previous
//
#include <hip/hip_runtime.h>
#include <hip/hip_bf16.h>

#define GLOBAL_AS __attribute__((address_space(1)))
#define LDS_AS    __attribute__((address_space(3)))

typedef __bf16 bf16_t;
typedef __bf16 bf16x8 __attribute__((ext_vector_type(8)));
typedef __bf16 bf16x4 __attribute__((ext_vector_type(4)));
typedef float  f32x4  __attribute__((ext_vector_type(4)));

static constexpr int Bb = 256;    // batch
static constexpr int Ss = 14;     // seq
static constexpr int Hh = 1024;   // hidden
static constexpr int Cc = 2513;   // classes
static constexpr int NXc = 3584;  // B*S
static constexpr int Kk = 1024;   // K (== F == H)

__device__ __forceinline__ float sigm(float x)   { return 1.0f / (1.0f + __expf(-x)); }
__device__ __forceinline__ float tanh_f(float x) { return 2.0f / (1.0f + __expf(-2.0f * x)) - 1.0f; }

// ---------------------------------------------------------------------------
// 128x128-tile bf16 GEMM: C[M,N] = A[M,K] @ B[N,K]^T, K=1024, BK=64.
// 1D grid with XCD 2D sub-rectangle partition: xcd=lin&7 owns rpg x cpg tiles,
// enumerated row-fast (col-major sweep) so a col's B-blocks are reused hot.
// EPI 0: XG store  — rows 4n+g; add row-bias; store bf16x4 to XG[n][col][4]
// EPI 1: LSTM cell — lane's 4 regs = gates (i,f,g,o) of (n,col); col=t*256+b;
//                    fused sigmoid/tanh state update, c fp32, h bf16.
// EPI 2: plain     — add col-bias, bounds-checked fp32 store (classifier).
// ---------------------------------------------------------------------------
template<int EPI>
__global__ __launch_bounds__(256, 2)
void gemm_bt(const bf16_t* __restrict__ A, const bf16_t* __restrict__ Bm,
             int N, int rpg, int cpg, int CG, int CB,
             const float* __restrict__ e_bias,
             bf16_t* __restrict__ xg_bf,
             float* __restrict__ fout,
             const float* __restrict__ c_src,
             float* __restrict__ c_dst,
             bf16_t* __restrict__ h_dst,
             int t_base)
{
    const int lin = blockIdx.x;
    const int xcd = lin & 7;
    const int per = lin >> 3;
    const int rg = xcd / CG, cg = xcd % CG;
    const int rb = rg * rpg + per % rpg;
    const int cb = cg * cpg + per / rpg;
    if (cb >= CB) return;                       // padded col groups

    __shared__ char smem[32768];                // A tile 16K | B tile 16K
    LDS_AS char* sA = (LDS_AS char*)smem;
    LDS_AS char* sB = sA + 16384;

    const int tid  = threadIdx.x;
    const int lane = tid & 63;
    const int wave = tid >> 6;
    const int row0 = rb * 128;
    const int col0 = cb * 128;
    const int mwb  = (wave >> 1) * 64;
    const int nwb  = (wave & 1) * 64;
    const int quad = lane >> 4;
    const int l15  = lane & 15;

    f32x4 acc[4][4] = {};

    for (int kb = 0; kb < Kk; kb += 64) {
        // ---- stage A,B tiles: 16B/lane, XOR-swizzled k-chunks ----
#pragma unroll
        for (int it = 0; it < 4; ++it) {
            int c  = it * 256 + tid;
            int m  = c >> 3;
            int kq = (c & 7) ^ (m & 7);
            const bf16_t* ga = A + (size_t)(row0 + m) * Kk + kb + kq * 8;
            int nr = col0 + m;
            if (EPI == 2) { if (nr >= N) nr = 0; }      // classifier N-edge clamp
            const bf16_t* gb = Bm + (size_t)nr * Kk + kb + kq * 8;
            LDS_AS char* la = sA + (size_t)(it * 256 + (tid & 192)) * 16;
            LDS_AS char* lb = sB + (size_t)(it * 256 + (tid & 192)) * 16;
            __builtin_amdgcn_global_load_lds((const GLOBAL_AS void*)ga, (LDS_AS void*)la, 16, 0, 0);
            __builtin_amdgcn_global_load_lds((const GLOBAL_AS void*)gb, (LDS_AS void*)lb, 16, 0, 0);
        }
        __syncthreads();

        // ---- compute: 2 k-steps x 16 MFMAs ----
#pragma unroll
        for (int kt = 0; kt < 2; ++kt) {
            bf16x8 af[4], bfr[4];
            const int kq = kt * 4 + quad;
#pragma unroll
            for (int i = 0; i < 4; ++i) {
                int ml = mwb + i * 16 + l15;
                af[i]  = *(const LDS_AS bf16x8*)(sA + (size_t)(ml * 8 + (kq ^ (ml & 7))) * 16);
                int nl = nwb + i * 16 + l15;
                bfr[i] = *(const LDS_AS bf16x8*)(sB + (size_t)(nl * 8 + (kq ^ (nl & 7))) * 16);
            }
#pragma unroll
            for (int i = 0; i < 4; ++i)
#pragma unroll
                for (int j = 0; j < 4; ++j)
                    acc[i][j] = __builtin_amdgcn_mfma_f32_16x16x32_bf16(af[i], bfr[j], acc[i][j], 0, 0, 0);
        }
        __syncthreads();
    }

    // ---- epilogue ----
#pragma unroll
    for (int im = 0; im < 4; ++im) {
#pragma unroll
        for (int jn = 0; jn < 4; ++jn) {
            const int rr  = row0 + mwb + im * 16 + quad * 4;  // 4 consecutive rows
            const int col = col0 + nwb + jn * 16 + l15;
            f32x4 v = acc[im][jn];
            if (EPI == 0) {
                const int n = rr >> 2;
                f32x4 bi = *(const f32x4*)(e_bias + n * 4);
                bf16x4 o;
                o[0] = (bf16_t)(v[0] + bi[0]); o[1] = (bf16_t)(v[1] + bi[1]);
                o[2] = (bf16_t)(v[2] + bi[2]); o[3] = (bf16_t)(v[3] + bi[3]);
                *(bf16x4*)(xg_bf + ((size_t)n * NXc + col) * 4) = o;
            } else if (EPI == 1) {
                const int n = rr >> 2;
                const int xgcol = col + (t_base << 8);
                bf16x4 xg4 = *(const bf16x4*)(xg_bf + ((size_t)n * NXc + xgcol) * 4);
                float gi = v[0] + (float)xg4[0];
                float gf = v[1] + (float)xg4[1];
                float gg = v[2] + (float)xg4[2];
                float go = v[3] + (float)xg4[3];
                const size_t sidx = (size_t)col * Hh + n;
                float c2 = sigm(gf) * c_src[sidx] + sigm(gi) * tanh_f(gg);
                float h2 = sigm(go) * tanh_f(c2);
                c_dst[sidx] = c2;
                h_dst[sidx] = (bf16_t)h2;
            } else {
                if (col < N) {
                    float bi = e_bias[col];
#pragma unroll
                    for (int g = 0; g < 4; ++g)
                        fout[(size_t)(rr + g) * N + col] = v[g] + bi;
                }
            }
        }
    }
}

// ---------------------------------------------------------------------------
// 64x64-tile EPI=1 kernel for small-N recurrent steps (roll: N=256 -> 256
// blocks instead of 64; unroll tails a<4). Same LDS swizzle scheme.
// ---------------------------------------------------------------------------
__global__ __launch_bounds__(256, 4)
void gemm_bt64(const bf16_t* __restrict__ A, const bf16_t* __restrict__ Bm,
               const bf16_t* __restrict__ xg_bf,
               const float* __restrict__ c_src, float* __restrict__ c_dst,
               bf16_t* __restrict__ h_dst, int t_base)
{
    __shared__ char smem[16384];
    LDS_AS char* sA = (LDS_AS char*)smem;
    LDS_AS char* sB = sA + 8192;
    const int tid = threadIdx.x, lane = tid & 63, wave = tid >> 6;
    const int row0 = blockIdx.x * 64, col0 = blockIdx.y * 64;
    const int mwb = (wave >> 1) * 32, nwb = (wave & 1) * 32;
    const int quad = lane >> 4, l15 = lane & 15;
    f32x4 acc[2][2] = {};

    for (int kb = 0; kb < Kk; kb += 64) {
#pragma unroll
        for (int it = 0; it < 2; ++it) {
            int c = it * 256 + tid;
            int m = c >> 3;
            int kq = (c & 7) ^ (m & 7);
            const bf16_t* ga = A + (size_t)(row0 + m) * Kk + kb + kq * 8;
            const bf16_t* gb = Bm + (size_t)(col0 + m) * Kk + kb + kq * 8;
            LDS_AS char* la = sA + (size_t)(it * 256 + (tid & 192)) * 16;
            LDS_AS char* lb = sB + (size_t)(it * 256 + (tid & 192)) * 16;
            __builtin_amdgcn_global_load_lds((const GLOBAL_AS void*)ga, (LDS_AS void*)la, 16, 0, 0);
            __builtin_amdgcn_global_load_lds((const GLOBAL_AS void*)gb, (LDS_AS void*)lb, 16, 0, 0);
        }
        __syncthreads();
#pragma unroll
        for (int kt = 0; kt < 2; ++kt) {
            bf16x8 af[2], bfr[2];
            const int kq = kt * 4 + quad;
#pragma unroll
            for (int i = 0; i < 2; ++i) {
                int ml = mwb + i * 16 + l15;
                af[i] = *(const LDS_AS bf16x8*)(sA + (size_t)(ml * 8 + (kq ^ (ml & 7))) * 16);
                int nl = nwb + i * 16 + l15;
                bfr[i] = *(const LDS_AS bf16x8*)(sB + (size_t)(nl * 8 + (kq ^ (nl & 7))) * 16);
            }
#pragma unroll
            for (int i = 0; i < 2; ++i)
#pragma unroll
                for (int j = 0; j < 2; ++j)
                    acc[i][j] = __builtin_amdgcn_mfma_f32_16x16x32_bf16(af[i], bfr[j], acc[i][j], 0, 0, 0);
        }
        __syncthreads();
    }

#pragma unroll
    for (int im = 0; im < 2; ++im)
#pragma unroll
        for (int jn = 0; jn < 2; ++jn) {
            const int rr  = row0 + mwb + im * 16 + quad * 4;
            const int col = col0 + nwb + jn * 16 + l15;
            f32x4 v = acc[im][jn];
            const int n = rr >> 2;
            const int xgcol = col + (t_base << 8);
            bf16x4 xg4 = *(const bf16x4*)(xg_bf + ((size_t)n * NXc + xgcol) * 4);
            float gi = v[0] + (float)xg4[0];
            float gf = v[1] + (float)xg4[1];
            float gg = v[2] + (float)xg4[2];
            float go = v[3] + (float)xg4[3];
            const size_t sidx = (size_t)col * Hh + n;
            float c2 = sigm(gf) * c_src[sidx] + sigm(gi) * tanh_f(gg);
            float h2 = sigm(go) * tanh_f(c2);
            c_dst[sidx] = c2;
            h_dst[sidx] = (bf16_t)h2;
        }
}

// ---------------------------------------------------------------------------
// Weight conversion: fp32 [4H,K] -> bf16 [4H,K] with row perm 4n+g <- g*H+n
// ---------------------------------------------------------------------------
__global__ void cvt_w(const float* __restrict__ a0, const float* __restrict__ a1,
                      const float* __restrict__ a2, const float* __restrict__ a3,
                      bf16_t* __restrict__ o0, bf16_t* __restrict__ o1,
                      bf16_t* __restrict__ o2, bf16_t* __restrict__ o3)
{
    int idx = blockIdx.x * 256 + threadIdx.x;          // 4 * 1,048,576 threads
    int mat = idx >> 20;
    int r   = (idx >> 8) & 4095;                       // output row (4n+g)
    int k4  = (idx & 255) * 4;
    int n = r >> 2, g = r & 3;
    const float* src = mat == 0 ? a0 : mat == 1 ? a1 : mat == 2 ? a2 : a3;
    bf16_t*      dst = mat == 0 ? o0 : mat == 1 ? o1 : mat == 2 ? o2 : o3;
    f32x4 v = *(const f32x4*)(src + (size_t)(g * Hh + n) * Kk + k4);
    bf16x4 o;
    o[0] = (bf16_t)v[0]; o[1] = (bf16_t)v[1]; o[2] = (bf16_t)v[2]; o[3] = (bf16_t)v[3];
    *(bf16x4*)(dst + (size_t)r * Kk + k4) = o;
}

__global__ void cvt_bias(const float* __restrict__ bih_r, const float* __restrict__ bhh_r,
                         const float* __restrict__ bih_u, const float* __restrict__ bhh_u,
                         float* __restrict__ br, float* __restrict__ bu)
{
    int r = blockIdx.x * 256 + threadIdx.x;            // 4096
    int n = r >> 2, g = r & 3;
    int ir = g * Hh + n;
    br[r] = bih_r[ir] + bhh_r[ir];
    bu[r] = bih_u[ir] + bhh_u[ir];
}

// x [b*14+s][f] fp32 -> x_b [s*256+b][f] bf16  (keeps EPI=1 XG reads coalesced)
__global__ void cvt_x(const float* __restrict__ src, bf16_t* __restrict__ dst)
{
    int idx = blockIdx.x * 256 + threadIdx.x;          // 3584*256 threads
    int f4  = (idx & 255) * 4;
    int row = idx >> 8;                                // b*14+s
    int s = row % 14, b = row / 14;
    f32x4 v = *(const f32x4*)(src + (size_t)row * Kk + f4);
    bf16x4 o;
    o[0] = (bf16_t)v[0]; o[1] = (bf16_t)v[1]; o[2] = (bf16_t)v[2]; o[3] = (bf16_t)v[3];
    *(bf16x4*)(dst + (size_t)(s * 256 + b) * Kk + f4) = o;
}

__global__ void cast_f32_bf16(const float* __restrict__ src, bf16_t* __restrict__ dst, int n4)
{
    int i = blockIdx.x * 256 + threadIdx.x;
    if (i < n4) {
        f32x4 v = *(const f32x4*)(src + (size_t)i * 4);
        bf16x4 o;
        o[0] = (bf16_t)v[0]; o[1] = (bf16_t)v[1]; o[2] = (bf16_t)v[2]; o[3] = (bf16_t)v[3];
        *(bf16x4*)(dst + (size_t)i * 4) = o;
    }
}

// preds[b*14+s][:] = Hu[(15-s)&1][s*256+b][:]   (16B per thread)
__global__ void gather_preds(const bf16_t* __restrict__ Hu0, const bf16_t* __restrict__ Hu1,
                             bf16_t* __restrict__ preds)
{
    int idx = blockIdx.x * 256 + threadIdx.x;          // 3584*128
    int h8  = (idx & 127) * 8;
    int row = idx >> 7;                                // b*14 + s
    int s = row % 14;
    int b = row / 14;
    const bf16_t* src = (((15 - s) & 1) ? Hu1 : Hu0) + (((size_t)(s * 256 + b)) << 10) + h8;
    *(uint4*)(preds + ((size_t)row << 10) + h8) = *(const uint4*)src;
}

// ---------------------------------------------------------------------------
extern "C" void kernel_launch(void* const* d_in, const int* in_sizes, int n_in,
                              void* d_out, int out_size, void* d_ws, size_t ws_size,
                              hipStream_t stream)
{
    const float* x_in  = (const float*)d_in[0];
    const float* Wih_r = (const float*)d_in[1];
    const float* Whh_r = (const float*)d_in[2];
    const float* bih_r = (const float*)d_in[3];
    const float* bhh_r = (const float*)d_in[4];
    const float* Wih_u = (const float*)d_in[5];
    const float* Whh_u = (const float*)d_in[6];
    const float* bih_u = (const float*)d_in[7];
    const float* bhh_u = (const float*)d_in[8];
    const float* Wc    = (const float*)d_in[9];
    const float* bc    = (const float*)d_in[10];
    float* out = (float*)d_out;

    char* ws = (char*)d_ws;
    size_t off = 0;
    auto alloc = [&](size_t bytes) -> char* {
        char* p = ws + off;
        off += (bytes + 255) & ~(size_t)255;
        return p;
    };

    const size_t BH = (size_t)Bb * Hh;                 // 262144 elems
    bf16_t* w_ih2  = (bf16_t*)alloc((size_t)8192 * Kk * 2);  // [roll 4096 | unroll 4096]
    bf16_t* w_hhr  = (bf16_t*)alloc((size_t)4096 * Kk * 2);
    bf16_t* w_hhu  = (bf16_t*)alloc((size_t)4096 * Kk * 2);
    bf16_t* wc_b   = (bf16_t*)alloc((size_t)Cc * Kk * 2);
    bf16_t* x_b    = (bf16_t*)alloc((size_t)NXc * Kk * 2);
    float*  bias2  = (float*)alloc(8192 * 4);                // [n][4] roll | unroll
    bf16_t* XG2    = (bf16_t*)alloc((size_t)2048 * NXc * 4 * 2); // [n'][col][4] bf16
    bf16_t* Hu0    = (bf16_t*)alloc((size_t)Ss * BH * 2);
    bf16_t* Hu1    = (bf16_t*)alloc((size_t)Ss * BH * 2);
    float*  Cu     = (float*)alloc((size_t)Ss * BH * 4);
    bf16_t* h0     = (bf16_t*)alloc(BH * 2);
    float*  c0     = (float*)alloc(BH * 4);
    bf16_t* preds  = (bf16_t*)alloc((size_t)NXc * Kk * 2);

    bf16_t* XGr = XG2;
    bf16_t* XGu = XG2 + (size_t)1024 * NXc * 4;

    hipMemsetAsync(h0, 0, BH * 2, stream);
    hipMemsetAsync(c0, 0, BH * 4, stream);

    // conversions
    cvt_w<<<16384, 256, 0, stream>>>(Wih_r, Whh_r, Wih_u, Whh_u,
                                     w_ih2, w_hhr, w_ih2 + (size_t)4096 * Kk, w_hhu);
    cvt_bias<<<16, 256, 0, stream>>>(bih_r, bhh_r, bih_u, bhh_u, bias2, bias2 + 4096);
    cvt_x<<<3584, 256, 0, stream>>>(x_in, x_b);
    cast_f32_bf16<<<(Cc * Kk / 4 + 255) / 256, 256, 0, stream>>>(Wc, wc_b, Cc * Kk / 4);

    // merged input-projection GEMM: [8192,3584] = W_ih2 @ x^T + bias -> XG2 bf16
    // RB=64, CB=28; RG=4,CG=2 -> rpg=16, cpg=14, grid 1792
    gemm_bt<0><<<1792, 256, 0, stream>>>(w_ih2, x_b, NXc, 16, 14, 2, 28,
                                         bias2, XG2, nullptr, nullptr, nullptr, nullptr, 0);

    // rolling LSTM: 14 sequential steps (64x64 tiles, 256 blocks each)
    for (int t = 0; t < Ss; ++t) {
        const bf16_t* hprev = (t == 0) ? h0 : (Hu0 + (size_t)(t - 1) * BH);
        const float*  csrc  = (t == 0) ? c0 : (Cu + (size_t)(t - 1) * BH);
        gemm_bt64<<<dim3(64, 4), 256, 0, stream>>>(w_hhr, hprev, XGr, csrc,
                                                   Cu + (size_t)t * BH,
                                                   Hu0 + (size_t)t * BH, t);
    }

    // unrolling LSTM: 15 batched steps over shrinking active-t prefix
    for (int j = 1; j <= 15; ++j) {
        int a = 16 - j; if (a > 14) a = 14;
        const bf16_t* hread = (j & 1) ? Hu0 : Hu1;
        bf16_t*       hwrit = (j & 1) ? Hu1 : Hu0;
        if (a >= 4) {
            int CB = 2 * a;
            int cpg = (CB + 3) / 4;                    // CG=4, RG=2, rpg=16
            int grid = 8 * 16 * cpg;
            gemm_bt<1><<<grid, 256, 0, stream>>>(w_hhu, hread, a * 256, 16, cpg, 4, CB,
                                                 nullptr, XGu, nullptr, Cu, Cu, hwrit, 0);
        } else {
            gemm_bt64<<<dim3(64, 4 * a), 256, 0, stream>>>(w_hhu, hread, XGu,
                                                           Cu, Cu, hwrit, 0);
        }
    }

    // gather preds [b*14+s][:] then classifier
    gather_preds<<<1792, 256, 0, stream>>>(Hu0, Hu1, preds);
    // RB=28, CB=20; RG=2,CG=4 -> rpg=14, cpg=5, grid 560
    gemm_bt<2><<<560, 256, 0, stream>>>(preds, wc_b, Cc, 14, 5, 4, 20,
                                        bc, nullptr, out, nullptr, nullptr, nullptr, 0);
}

// Round 3
// 872.117 us; speedup vs baseline: 1.5108x; 1.0900x over previous
//
#include <hip/hip_runtime.h>
#include <hip/hip_bf16.h>

#define GLOBAL_AS __attribute__((address_space(1)))
#define LDS_AS    __attribute__((address_space(3)))

typedef __bf16 bf16_t;
typedef __bf16 bf16x8 __attribute__((ext_vector_type(8)));
typedef __bf16 bf16x4 __attribute__((ext_vector_type(4)));
typedef float  f32x4  __attribute__((ext_vector_type(4)));
typedef _Float16 fp16_t;

static constexpr int Bb = 256;    // batch
static constexpr int Ss = 14;     // seq
static constexpr int Hh = 1024;   // hidden
static constexpr int Cc = 2513;   // classes
static constexpr int NXc = 3584;  // B*S
static constexpr int Kk = 1024;   // K (== F == H)

__device__ __forceinline__ float sigm(float x)   { return 1.0f / (1.0f + __expf(-x)); }
__device__ __forceinline__ float tanh_f(float x) { return 2.0f / (1.0f + __expf(-2.0f * x)) - 1.0f; }

// ---------------------------------------------------------------------------
// 128x128-tile bf16 GEMM: C[M,N] = A[M,K] @ B[N,K]^T, K=1024, BK=64.
// XCD 2D sub-rectangle partition (xcd=lin&7 owns rpg x cpg tiles, row-fast).
// EPI 0: XG store — rows 4n+g; add row-bias; store bf16x4 to XG[n][col][4]
// EPI 2: classifier — A rows remapped row -> (row%14)*256 + row/14 (reads the
//        final-h buffer directly, no gather); add col-bias; fp32 store.
// ---------------------------------------------------------------------------
template<int EPI>
__global__ __launch_bounds__(256, 2)
void gemm_bt(const bf16_t* __restrict__ A, const bf16_t* __restrict__ Bm,
             int N, int rpg, int cpg, int CG, int CB,
             const float* __restrict__ e_bias,
             bf16_t* __restrict__ xg_bf,
             float* __restrict__ fout)
{
    const int lin = blockIdx.x;
    const int xcd = lin & 7;
    const int per = lin >> 3;
    const int rg = xcd / CG, cg = xcd % CG;
    const int rb = rg * rpg + per % rpg;
    const int cb = cg * cpg + per / rpg;
    if (cb >= CB) return;

    __shared__ char smem[32768];                // A tile 16K | B tile 16K
    LDS_AS char* sA = (LDS_AS char*)smem;
    LDS_AS char* sB = sA + 16384;

    const int tid  = threadIdx.x;
    const int lane = tid & 63;
    const int wave = tid >> 6;
    const int row0 = rb * 128;
    const int col0 = cb * 128;
    const int mwb  = (wave >> 1) * 64;
    const int nwb  = (wave & 1) * 64;
    const int quad = lane >> 4;
    const int l15  = lane & 15;

    f32x4 acc[4][4] = {};

    for (int kb = 0; kb < Kk; kb += 64) {
#pragma unroll
        for (int it = 0; it < 4; ++it) {
            int c  = it * 256 + tid;
            int m  = c >> 3;
            int kq = (c & 7) ^ (m & 7);
            size_t arow;
            if (EPI == 2) {                      // A-row remap: b*14+s -> s*256+b
                int row = row0 + m;
                int bb = row / 14;
                int ss = row - bb * 14;
                arow = (size_t)(ss * 256 + bb);
            } else {
                arow = (size_t)(row0 + m);
            }
            const bf16_t* ga = A + arow * Kk + kb + kq * 8;
            int nr = col0 + m;
            if (EPI == 2) { if (nr >= N) nr = 0; }
            const bf16_t* gb = Bm + (size_t)nr * Kk + kb + kq * 8;
            LDS_AS char* la = sA + (size_t)(it * 256 + (tid & 192)) * 16;
            LDS_AS char* lb = sB + (size_t)(it * 256 + (tid & 192)) * 16;
            __builtin_amdgcn_global_load_lds((const GLOBAL_AS void*)ga, (LDS_AS void*)la, 16, 0, 0);
            __builtin_amdgcn_global_load_lds((const GLOBAL_AS void*)gb, (LDS_AS void*)lb, 16, 0, 0);
        }
        __syncthreads();

#pragma unroll
        for (int kt = 0; kt < 2; ++kt) {
            bf16x8 af[4], bfr[4];
            const int kq = kt * 4 + quad;
#pragma unroll
            for (int i = 0; i < 4; ++i) {
                int ml = mwb + i * 16 + l15;
                af[i]  = *(const LDS_AS bf16x8*)(sA + (size_t)(ml * 8 + (kq ^ (ml & 7))) * 16);
                int nl = nwb + i * 16 + l15;
                bfr[i] = *(const LDS_AS bf16x8*)(sB + (size_t)(nl * 8 + (kq ^ (nl & 7))) * 16);
            }
#pragma unroll
            for (int i = 0; i < 4; ++i)
#pragma unroll
                for (int j = 0; j < 4; ++j)
                    acc[i][j] = __builtin_amdgcn_mfma_f32_16x16x32_bf16(af[i], bfr[j], acc[i][j], 0, 0, 0);
        }
        __syncthreads();
    }

#pragma unroll
    for (int im = 0; im < 4; ++im) {
#pragma unroll
        for (int jn = 0; jn < 4; ++jn) {
            const int rr  = row0 + mwb + im * 16 + quad * 4;
            const int col = col0 + nwb + jn * 16 + l15;
            f32x4 v = acc[im][jn];
            if (EPI == 0) {
                const int n = rr >> 2;
                f32x4 bi = *(const f32x4*)(e_bias + n * 4);
                bf16x4 o;
                o[0] = (bf16_t)(v[0] + bi[0]); o[1] = (bf16_t)(v[1] + bi[1]);
                o[2] = (bf16_t)(v[2] + bi[2]); o[3] = (bf16_t)(v[3] + bi[3]);
                *(bf16x4*)(xg_bf + ((size_t)n * NXc + col) * 4) = o;
            } else {
                if (col < N) {
                    float bi = e_bias[col];
#pragma unroll
                    for (int g = 0; g < 4; ++g)
                        fout[(size_t)(rr + g) * N + col] = v[g] + bi;
                }
            }
        }
    }
}

// ---------------------------------------------------------------------------
// Merged recurrent step (skewed schedule, global step k):
//   unroll col-blocks [0, UCB): A=Au, advance t<=k-2 lockstep
//   roll col-blocks  [UCB, CB): A=Ar, compute hs[k-1] (2 col-blocks, k<=14)
// h ping-pong bf16, c ping-pong fp16. Lane's 4 acc regs = gates (i,f,g,o).
// ---------------------------------------------------------------------------
struct StepArgs {
    const bf16_t* Au;     // unroll weight [4096,1024] perm-rows
    const bf16_t* Ar;     // roll weight
    const bf16_t* Bh;     // h read base (P[(k-1)&1]; h0 for k==1)
    const bf16_t* xg_u;   // XGu [n][col][4]
    const bf16_t* xg_r;   // XGr
    const fp16_t* c_r;    // c read base
    fp16_t*       c_w;    // c write base
    bf16_t*       h_w;    // h write base
    int UCB;              // unroll col-blocks (2a)
    int b_off;            // roll B col offset   = (k-2)*256
    int xg_off;           // roll xg col offset  = (k-1)*256
    int cr_off;           // roll c-read offset  = (k-2)*256
    int cw_off;           // roll c/h-write off  = (k-1)*256
    int CB, cpg;          // total col-blocks, cols per XCD group (CG=4,RG=2)
};

__global__ __launch_bounds__(256, 2)
void lstm_step(StepArgs p)
{
    const int lin = blockIdx.x;
    const int xcd = lin & 7;
    const int per = lin >> 3;
    const int rb = (xcd >> 2) * 16 + (per & 15);
    const int cb = (xcd & 3) * p.cpg + (per >> 4);
    if (cb >= p.CB) return;

    const bool roll = (cb >= p.UCB);
    const int  colb = roll ? (cb - p.UCB) : cb;
    const bf16_t* A = roll ? p.Ar : p.Au;
    const int bcol0 = colb * 128 + (roll ? p.b_off : 0);

    __shared__ char smem[32768];
    LDS_AS char* sA = (LDS_AS char*)smem;
    LDS_AS char* sB = sA + 16384;

    const int tid  = threadIdx.x;
    const int lane = tid & 63;
    const int wave = tid >> 6;
    const int row0 = rb * 128;
    const int mwb  = (wave >> 1) * 64;
    const int nwb  = (wave & 1) * 64;
    const int quad = lane >> 4;
    const int l15  = lane & 15;

    f32x4 acc[4][4] = {};

    for (int kb = 0; kb < Kk; kb += 64) {
#pragma unroll
        for (int it = 0; it < 4; ++it) {
            int c  = it * 256 + tid;
            int m  = c >> 3;
            int kq = (c & 7) ^ (m & 7);
            const bf16_t* ga = A    + (size_t)(row0  + m) * Kk + kb + kq * 8;
            const bf16_t* gb = p.Bh + (size_t)(bcol0 + m) * Kk + kb + kq * 8;
            LDS_AS char* la = sA + (size_t)(it * 256 + (tid & 192)) * 16;
            LDS_AS char* lb = sB + (size_t)(it * 256 + (tid & 192)) * 16;
            __builtin_amdgcn_global_load_lds((const GLOBAL_AS void*)ga, (LDS_AS void*)la, 16, 0, 0);
            __builtin_amdgcn_global_load_lds((const GLOBAL_AS void*)gb, (LDS_AS void*)lb, 16, 0, 0);
        }
        __syncthreads();

#pragma unroll
        for (int kt = 0; kt < 2; ++kt) {
            bf16x8 af[4], bfr[4];
            const int kq = kt * 4 + quad;
#pragma unroll
            for (int i = 0; i < 4; ++i) {
                int ml = mwb + i * 16 + l15;
                af[i]  = *(const LDS_AS bf16x8*)(sA + (size_t)(ml * 8 + (kq ^ (ml & 7))) * 16);
                int nl = nwb + i * 16 + l15;
                bfr[i] = *(const LDS_AS bf16x8*)(sB + (size_t)(nl * 8 + (kq ^ (nl & 7))) * 16);
            }
#pragma unroll
            for (int i = 0; i < 4; ++i)
#pragma unroll
                for (int j = 0; j < 4; ++j)
                    acc[i][j] = __builtin_amdgcn_mfma_f32_16x16x32_bf16(af[i], bfr[j], acc[i][j], 0, 0, 0);
        }
        __syncthreads();
    }

    const bf16_t* xg = roll ? p.xg_r : p.xg_u;
    const int xo = roll ? p.xg_off : 0;
    const int cro = roll ? p.cr_off : 0;
    const int cwo = roll ? p.cw_off : 0;

#pragma unroll
    for (int im = 0; im < 4; ++im) {
#pragma unroll
        for (int jn = 0; jn < 4; ++jn) {
            const int rr  = row0 + mwb + im * 16 + quad * 4;
            const int col = colb * 128 + nwb + jn * 16 + l15;
            f32x4 v = acc[im][jn];
            const int n = rr >> 2;
            bf16x4 xg4 = *(const bf16x4*)(xg + ((size_t)n * NXc + (col + xo)) * 4);
            float gi = v[0] + (float)xg4[0];
            float gf = v[1] + (float)xg4[1];
            float gg = v[2] + (float)xg4[2];
            float go = v[3] + (float)xg4[3];
            const size_t sr = (size_t)(col + cro) * Hh + n;
            const size_t sw = (size_t)(col + cwo) * Hh + n;
            float c2 = sigm(gf) * (float)p.c_r[sr] + sigm(gi) * tanh_f(gg);
            float h2 = sigm(go) * tanh_f(c2);
            p.c_w[sw] = (fp16_t)c2;
            p.h_w[sw] = (bf16_t)h2;
        }
    }
}

// ---------------------------------------------------------------------------
// Weight conversion: fp32 [4H,K] -> bf16 [4H,K] with row perm 4n+g <- g*H+n
// ---------------------------------------------------------------------------
__global__ void cvt_w(const float* __restrict__ a0, const float* __restrict__ a1,
                      const float* __restrict__ a2, const float* __restrict__ a3,
                      bf16_t* __restrict__ o0, bf16_t* __restrict__ o1,
                      bf16_t* __restrict__ o2, bf16_t* __restrict__ o3)
{
    int idx = blockIdx.x * 256 + threadIdx.x;
    int mat = idx >> 20;
    int r   = (idx >> 8) & 4095;
    int k4  = (idx & 255) * 4;
    int n = r >> 2, g = r & 3;
    const float* src = mat == 0 ? a0 : mat == 1 ? a1 : mat == 2 ? a2 : a3;
    bf16_t*      dst = mat == 0 ? o0 : mat == 1 ? o1 : mat == 2 ? o2 : o3;
    f32x4 v = *(const f32x4*)(src + (size_t)(g * Hh + n) * Kk + k4);
    bf16x4 o;
    o[0] = (bf16_t)v[0]; o[1] = (bf16_t)v[1]; o[2] = (bf16_t)v[2]; o[3] = (bf16_t)v[3];
    *(bf16x4*)(dst + (size_t)r * Kk + k4) = o;
}

__global__ void cvt_bias(const float* __restrict__ bih_r, const float* __restrict__ bhh_r,
                         const float* __restrict__ bih_u, const float* __restrict__ bhh_u,
                         float* __restrict__ br, float* __restrict__ bu)
{
    int r = blockIdx.x * 256 + threadIdx.x;
    int n = r >> 2, g = r & 3;
    int ir = g * Hh + n;
    br[r] = bih_r[ir] + bhh_r[ir];
    bu[r] = bih_u[ir] + bhh_u[ir];
}

// x [b*14+s][f] fp32 -> x_b [s*256+b][f] bf16
__global__ void cvt_x(const float* __restrict__ src, bf16_t* __restrict__ dst)
{
    int idx = blockIdx.x * 256 + threadIdx.x;
    int f4  = (idx & 255) * 4;
    int row = idx >> 8;
    int s = row % 14, b = row / 14;
    f32x4 v = *(const f32x4*)(src + (size_t)row * Kk + f4);
    bf16x4 o;
    o[0] = (bf16_t)v[0]; o[1] = (bf16_t)v[1]; o[2] = (bf16_t)v[2]; o[3] = (bf16_t)v[3];
    *(bf16x4*)(dst + (size_t)(s * 256 + b) * Kk + f4) = o;
}

__global__ void cast_f32_bf16(const float* __restrict__ src, bf16_t* __restrict__ dst, int n4)
{
    int i = blockIdx.x * 256 + threadIdx.x;
    if (i < n4) {
        f32x4 v = *(const f32x4*)(src + (size_t)i * 4);
        bf16x4 o;
        o[0] = (bf16_t)v[0]; o[1] = (bf16_t)v[1]; o[2] = (bf16_t)v[2]; o[3] = (bf16_t)v[3];
        *(bf16x4*)(dst + (size_t)i * 4) = o;
    }
}

// ---------------------------------------------------------------------------
extern "C" void kernel_launch(void* const* d_in, const int* in_sizes, int n_in,
                              void* d_out, int out_size, void* d_ws, size_t ws_size,
                              hipStream_t stream)
{
    const float* x_in  = (const float*)d_in[0];
    const float* Wih_r = (const float*)d_in[1];
    const float* Whh_r = (const float*)d_in[2];
    const float* bih_r = (const float*)d_in[3];
    const float* bhh_r = (const float*)d_in[4];
    const float* Wih_u = (const float*)d_in[5];
    const float* Whh_u = (const float*)d_in[6];
    const float* bih_u = (const float*)d_in[7];
    const float* bhh_u = (const float*)d_in[8];
    const float* Wc    = (const float*)d_in[9];
    const float* bc    = (const float*)d_in[10];
    float* out = (float*)d_out;

    char* ws = (char*)d_ws;
    size_t off = 0;
    auto alloc = [&](size_t bytes) -> char* {
        char* p = ws + off;
        off += (bytes + 255) & ~(size_t)255;
        return p;
    };

    const size_t BH = (size_t)Bb * Hh;                 // 262144 elems
    bf16_t* w_ih2  = (bf16_t*)alloc((size_t)8192 * Kk * 2);  // [roll | unroll]
    bf16_t* w_hhr  = (bf16_t*)alloc((size_t)4096 * Kk * 2);
    bf16_t* w_hhu  = (bf16_t*)alloc((size_t)4096 * Kk * 2);
    bf16_t* wc_b   = (bf16_t*)alloc((size_t)Cc * Kk * 2);
    bf16_t* x_b    = (bf16_t*)alloc((size_t)NXc * Kk * 2);
    float*  bias2  = (float*)alloc(8192 * 4);
    bf16_t* XG2    = (bf16_t*)alloc((size_t)2048 * NXc * 4 * 2);
    bf16_t* P0     = (bf16_t*)alloc((size_t)Ss * BH * 2);
    bf16_t* P1     = (bf16_t*)alloc((size_t)Ss * BH * 2);
    fp16_t* Cp0    = (fp16_t*)alloc((size_t)Ss * BH * 2);
    fp16_t* Cp1    = (fp16_t*)alloc((size_t)Ss * BH * 2);
    bf16_t* h0     = (bf16_t*)alloc(BH * 2);
    fp16_t* c0     = (fp16_t*)alloc(BH * 2);

    bf16_t* XGr = XG2;
    bf16_t* XGu = XG2 + (size_t)1024 * NXc * 4;
    bf16_t* P[2] = {P0, P1};
    fp16_t* Cp[2] = {Cp0, Cp1};

    hipMemsetAsync(h0, 0, BH * 2, stream);
    hipMemsetAsync(c0, 0, BH * 2, stream);

    // conversions
    cvt_w<<<16384, 256, 0, stream>>>(Wih_r, Whh_r, Wih_u, Whh_u,
                                     w_ih2, w_hhr, w_ih2 + (size_t)4096 * Kk, w_hhu);
    cvt_bias<<<16, 256, 0, stream>>>(bih_r, bhh_r, bih_u, bhh_u, bias2, bias2 + 4096);
    cvt_x<<<3584, 256, 0, stream>>>(x_in, x_b);
    cast_f32_bf16<<<(Cc * Kk / 4 + 255) / 256, 256, 0, stream>>>(Wc, wc_b, Cc * Kk / 4);

    // merged input-projection GEMM: [8192,3584] -> XG2 bf16 (RG=4,CG=2)
    gemm_bt<0><<<1792, 256, 0, stream>>>(w_ih2, x_b, NXc, 16, 14, 2, 28,
                                         bias2, XG2, nullptr);

    // skewed recurrent schedule: 16 global steps, roll + lockstep unroll merged
    for (int k = 1; k <= 16; ++k) {
        int a = (k - 1 < 14) ? (k - 1) : 14;
        int rollk = (k <= 14) ? 1 : 0;
        StepArgs p;
        p.Au = w_hhu;  p.Ar = w_hhr;
        p.Bh = (k == 1) ? h0 : P[(k - 1) & 1];
        p.xg_u = XGu;  p.xg_r = XGr;
        p.c_r = (k == 1) ? c0 : Cp[(k - 1) & 1];
        p.c_w = Cp[k & 1];
        p.h_w = P[k & 1];
        p.UCB = 2 * a;
        p.b_off  = (k >= 2) ? (k - 2) * 256 : 0;
        p.xg_off = (k - 1) * 256;
        p.cr_off = (k >= 2) ? (k - 2) * 256 : 0;
        p.cw_off = (k - 1) * 256;
        p.CB  = p.UCB + 2 * rollk;
        p.cpg = (p.CB + 3) >> 2;
        lstm_step<<<8 * 16 * p.cpg, 256, 0, stream>>>(p);
    }

    // classifier: A = final h states in P[0] (A-row remap), out [3584,2513]
    gemm_bt<2><<<560, 256, 0, stream>>>(P[0], wc_b, Cc, 14, 5, 4, 20,
                                        bc, nullptr, out);
}